// Round 1
// baseline (43.975 us; speedup 1.0000x reference)
//
#include <hip/hip_runtime.h>
#include <hip/hip_bf16.h>

// Problem constants (from reference)
#define NB_LABELS 10
#define NB_EDGE_LABELS 4
#define N1 79
#define MP1 80           // n+1 = m+1 = 80
#define NTOT 6400        // 80*80
#define NODE_INS_DEL 0.03f
#define SINKHORN_ITERS 10

// ws float layout:
//  [0..6400)      v  (Sinkhorn result, row-major (i_g1, l_g2))
//  [6400..6425)   T  (5x5 edge-pair cost table, row-major)
//  [6425]         cv = c . v
//  [6432..6512)   per-j partial sums of v_r * u_r
#define WS_V    0
#define WS_T    6400
#define WS_CV   6425
#define WS_PJ   6432

// ---------------------------------------------------------------------------
// K1: build cost tables, c vector, S = exp(-0.5 c), 10 Sinkhorn iterations,
// write v, T, and c.v to workspace. Single block; everything lives in LDS.
// ---------------------------------------------------------------------------
__global__ __launch_bounds__(1024) void k_setup_sinkhorn(
    const int* __restrict__ Ag1, const int* __restrict__ Ag2,
    const int* __restrict__ l1, const int* __restrict__ l2,
    const float* __restrict__ nw, const float* __restrict__ ew,
    float* __restrict__ ws)
{
    __shared__ float X[MP1][MP1 + 1];   // 80x81 padded
    __shared__ float cL[NTOT];
    __shared__ float nodeC[NB_LABELS][NB_LABELS];
    __shared__ float T[25];
    __shared__ float rsum[MP1];
    __shared__ float red[MP1][8];
    __shared__ int   lab1[MP1];
    __shared__ int   lab2[MP1];
    __shared__ float partial[16];

    const int t = threadIdx.x;

    // node_costs: symmetric from upper-tri vec (triu_indices order), diag 0
    if (t < NB_LABELS * NB_LABELS) {
        int i = t / NB_LABELS, j = t % NB_LABELS;
        float val = 0.f;
        if (i != j) {
            int a = min(i, j), b = max(i, j);
            int p = a * (NB_LABELS - 1) - a * (a - 1) / 2 + (b - a - 1);
            val = fmaxf(nw[p], 0.f);
        }
        nodeC[i][j] = val;
    }
    // edge table 5x5: T[0][0]=0, T[0][b]=T[a][0]=ins_del, T[a][b]=edge_costs[a-1][b-1]
    if (t >= 128 && t < 153) {
        int q = t - 128;
        int a = q / 5, b = q % 5;
        float val;
        if (a == 0 && b == 0)       val = 0.f;
        else if (a == 0 || b == 0)  val = fmaxf(ew[NB_EDGE_LABELS * (NB_EDGE_LABELS - 1) / 2], 0.f);
        else if (a == b)            val = 0.f;
        else {
            int x = min(a, b) - 1, y = max(a, b) - 1;
            int p = x * (NB_EDGE_LABELS - 1) - x * (x - 1) / 2 + (y - x - 1);
            val = fmaxf(ew[p], 0.f);
        }
        T[q] = val;
    }
    if (t >= 192 && t < 192 + N1) {
        int q = t - 192;
        lab1[q] = l1[q];
        lab2[q] = l2[q];
    }
    __syncthreads();

    // c vector + X init
    for (int r = t; r < NTOT; r += 1024) {
        int i = r / MP1, j = r % MP1;
        float cv;
        if (i < N1 && j < N1)           cv = nodeC[lab1[i]][lab2[j]];
        else if (i == N1 && j == N1)    cv = 0.f;
        else                            cv = NODE_INS_DEL;
        cL[r] = cv;
        X[i][j] = expf(-0.5f * cv);
    }

    // Sinkhorn: row normalize then column normalize, 10x
    for (int it = 0; it < SINKHORN_ITERS; ++it) {
        // ---- row sums
        __syncthreads();
        if (t < 640) {
            int i = t >> 3, p = t & 7;
            float s = 0.f;
            int base = p * 10;
            #pragma unroll
            for (int q = 0; q < 10; ++q) s += X[i][base + q];
            red[i][p] = s;
        }
        __syncthreads();
        if (t < MP1) {
            float s = 0.f;
            #pragma unroll
            for (int p = 0; p < 8; ++p) s += red[t][p];
            rsum[t] = 1.0f / s;
        }
        __syncthreads();
        for (int r = t; r < NTOT; r += 1024) {
            int i = r / MP1, j = r % MP1;
            X[i][j] *= rsum[i];
        }
        // ---- col sums
        __syncthreads();
        if (t < 640) {
            int j = t >> 3, p = t & 7;
            float s = 0.f;
            #pragma unroll
            for (int q = 0; q < 10; ++q) s += X[p * 10 + q][j];
            red[j][p] = s;
        }
        __syncthreads();
        if (t < MP1) {
            float s = 0.f;
            #pragma unroll
            for (int p = 0; p < 8; ++p) s += red[t][p];
            rsum[t] = 1.0f / s;
        }
        __syncthreads();
        for (int r = t; r < NTOT; r += 1024) {
            int i = r / MP1, j = r % MP1;
            X[i][j] *= rsum[j];
        }
    }

    // write v, T; compute c.v
    __syncthreads();
    float loc = 0.f;
    for (int r = t; r < NTOT; r += 1024) {
        int i = r / MP1, j = r % MP1;
        float vv = X[i][j];
        ws[WS_V + r] = vv;
        loc += cL[r] * vv;
    }
    if (t < 25) ws[WS_T + t] = T[t];

    // block reduction of loc (16 waves)
    #pragma unroll
    for (int off = 32; off > 0; off >>= 1) loc += __shfl_down(loc, off, 64);
    if ((t & 63) == 0) partial[t >> 6] = loc;
    __syncthreads();
    if (t == 0) {
        float s = 0.f;
        #pragma unroll
        for (int w = 0; w < 16; ++w) s += partial[w];
        ws[WS_CV] = s;
    }
}

// ---------------------------------------------------------------------------
// K2: quadratic form, factored per j (graph-1 row index of the GED C-matrix).
//   u_{j,k} = sum_{i,l} T[A1[i,j], A2[k,l]] v[i,l]  -  diag term
//           = sum_l G_j[A2pad[k,l]][l]              (G_j[b][l] = sum_i T[a1col[i],b] v[i,l])
// Per-j partial of sum_k v_{j,k} * u_{j,k} is written to ws.
// ---------------------------------------------------------------------------
__global__ __launch_bounds__(256) void k_quad(
    const int* __restrict__ Ag1, const int* __restrict__ Ag2,
    float* __restrict__ ws)
{
    __shared__ float T5[25];
    __shared__ int   a1col[MP1];
    __shared__ float Gp[3][5][MP1];
    __shared__ float G[5][MP1];
    __shared__ float Up[3][MP1];
    __shared__ float wred[256];

    const float* v = ws + WS_V;
    const int j = blockIdx.x;     // 0..79
    const int t = threadIdx.x;

    if (t < 25) T5[t] = ws[WS_T + t];
    if (t < MP1) a1col[t] = (t < N1 && j < N1) ? Ag1[t * N1 + j] : 0;
    __syncthreads();

    // build G[b][l] (i-range split 3 ways over 240 threads)
    if (t < 240) {
        int l = t % MP1, p = t / MP1;
        int i0 = p * 27, i1 = min(i0 + 27, MP1);
        float g0 = 0, g1 = 0, g2 = 0, g3 = 0, g4 = 0;
        for (int i = i0; i < i1; ++i) {
            int a1 = a1col[i];
            float vv = v[i * MP1 + l];
            const float* Tr = &T5[a1 * 5];
            g0 = fmaf(Tr[0], vv, g0);
            g1 = fmaf(Tr[1], vv, g1);
            g2 = fmaf(Tr[2], vv, g2);
            g3 = fmaf(Tr[3], vv, g3);
            g4 = fmaf(Tr[4], vv, g4);
        }
        Gp[p][0][l] = g0; Gp[p][1][l] = g1; Gp[p][2][l] = g2;
        Gp[p][3][l] = g3; Gp[p][4][l] = g4;
    }
    __syncthreads();
    if (t < MP1) {
        #pragma unroll
        for (int b = 0; b < 5; ++b)
            G[b][t] = Gp[0][b][t] + Gp[1][b][t] + Gp[2][b][t];
    }
    __syncthreads();

    // u_{j,k} = sum_l G[a2(k,l)][l]   (l-range split 3 ways)
    if (t < 240) {
        int k = t % MP1, p = t / MP1;
        int l0 = p * 27, l1e = min(l0 + 27, MP1);
        float s = 0.f;
        for (int l = l0; l < l1e; ++l) {
            int a2 = (k < N1 && l < N1) ? Ag2[k * N1 + l] : 0;
            s += G[a2][l];
        }
        Up[p][k] = s;
    }
    __syncthreads();

    float w = 0.f;
    if (t < MP1) {
        int k = t;
        float u = Up[0][k] + Up[1][k] + Up[2][k];
        int a1d = (j < N1) ? Ag1[j * N1 + j] : 0;
        int a2d = (k < N1) ? Ag2[k * N1 + k] : 0;
        float vr = v[j * MP1 + k];
        u -= T5[a1d * 5 + a2d] * vr;    // remove diagonal (r==s) term
        w = vr * u;
    }
    wred[t] = w;
    __syncthreads();
    #pragma unroll
    for (int s2 = 128; s2 > 0; s2 >>= 1) {
        if (t < s2) wred[t] += wred[t + s2];
        __syncthreads();
    }
    if (t == 0) ws[WS_PJ + j] = wred[0];
}

// ---------------------------------------------------------------------------
// K3: deterministic final reduce: ged = cv + 0.5 * sum_j partial_j
// ---------------------------------------------------------------------------
__global__ __launch_bounds__(128) void k_final(
    const float* __restrict__ ws, float* __restrict__ dout)
{
    __shared__ float red[128];
    int t = threadIdx.x;
    red[t] = (t < MP1) ? ws[WS_PJ + t] : 0.f;
    __syncthreads();
    #pragma unroll
    for (int s = 64; s > 0; s >>= 1) {
        if (t < s) red[t] += red[t + s];
        __syncthreads();
    }
    if (t == 0) dout[0] = ws[WS_CV] + 0.5f * red[0];
}

extern "C" void kernel_launch(void* const* d_in, const int* in_sizes, int n_in,
                              void* d_out, int out_size, void* d_ws, size_t ws_size,
                              hipStream_t stream) {
    const int*   Ag1 = (const int*)d_in[0];
    const int*   Ag2 = (const int*)d_in[1];
    const int*   l1  = (const int*)d_in[2];
    const int*   l2  = (const int*)d_in[3];
    const float* nw  = (const float*)d_in[4];
    const float* ew  = (const float*)d_in[5];
    float* out = (float*)d_out;
    float* ws  = (float*)d_ws;

    k_setup_sinkhorn<<<1, 1024, 0, stream>>>(Ag1, Ag2, l1, l2, nw, ew, ws);
    k_quad<<<MP1, 256, 0, stream>>>(Ag1, Ag2, ws);
    k_final<<<1, 128, 0, stream>>>(ws, out);
}

// Round 2
// 32.834 us; speedup vs baseline: 1.3393x; 1.3393x over previous
//
#include <hip/hip_runtime.h>
#include <hip/hip_bf16.h>

// Problem constants (from reference)
#define NB_LABELS 10
#define NB_EDGE_LABELS 4
#define N1 79
#define MP1 80           // n+1 = m+1 = 80
#define NTOT 6400        // 80*80
#define NODE_INS_DEL 0.03f
#define SINKHORN_ITERS 10

// ws float layout:
//  [0..6400)      v  (Sinkhorn result, row-major (i_g1, l_g2))
//  [6400..6425)   T  (5x5 edge-pair cost table, row-major)
//  [6425]         cv = c . v
//  [6428]         (int) arrival counter for K2's fused final reduction
//  [6432..6512)   per-j partial sums of v_r * u_r
#define WS_V    0
#define WS_T    6400
#define WS_CV   6425
#define WS_CNT  6428
#define WS_PJ   6432

// ---------------------------------------------------------------------------
// K1: Sinkhorn in scaling-vector form. X = diag(r) S diag(c) with
//   r <- 1/(S c) ; c <- 1/(S^T r)   (exactly row-norm-then-col-norm)
// S and S^T live in registers: thread (a,p) (a=t>>3, p=t&7) holds
//   s[q]  = S[a][10p+q]   and   st[q] = S[10p+q][a].
// Both matvec reductions are p-axis only -> 3 intra-wave shfl_xor each.
// r/c vectors live in a [8][12]-padded LDS layout for aligned float4 reads.
// Writes v, T, c.v to ws and zeroes the arrival counter.
// ---------------------------------------------------------------------------
__global__ __launch_bounds__(640) void k1_sinkhorn(
    const int* __restrict__ l1, const int* __restrict__ l2,
    const float* __restrict__ nw, const float* __restrict__ ew,
    float* __restrict__ ws)
{
    __shared__ float nodeC[NB_LABELS * NB_LABELS];
    __shared__ float T5[25];
    __shared__ int   lab1[MP1], lab2[MP1];
    __shared__ __align__(16) float c2[8 * 12];   // c vector, padded per p-group
    __shared__ __align__(16) float r2[8 * 12];   // r vector, padded per p-group
    __shared__ float red[10];

    const int t = threadIdx.x;

    // node_costs: symmetric from upper-tri vec (triu_indices order), diag 0
    if (t < NB_LABELS * NB_LABELS) {
        int i = t / NB_LABELS, j = t % NB_LABELS;
        float val = 0.f;
        if (i != j) {
            int a = min(i, j), b = max(i, j);
            int p = a * (NB_LABELS - 1) - a * (a - 1) / 2 + (b - a - 1);
            val = fmaxf(nw[p], 0.f);
        }
        nodeC[t] = val;
    }
    // edge table 5x5
    if (t >= 128 && t < 153) {
        int q = t - 128;
        int a = q / 5, b = q % 5;
        float val;
        if (a == 0 && b == 0)       val = 0.f;
        else if (a == 0 || b == 0)  val = fmaxf(ew[NB_EDGE_LABELS * (NB_EDGE_LABELS - 1) / 2], 0.f);
        else if (a == b)            val = 0.f;
        else {
            int x = min(a, b) - 1, y = max(a, b) - 1;
            int p = x * (NB_EDGE_LABELS - 1) - x * (x - 1) / 2 + (y - x - 1);
            val = fmaxf(ew[p], 0.f);
        }
        T5[q] = val;
    }
    if (t >= 160 && t < 160 + N1) {
        lab1[t - 160] = l1[t - 160];
        lab2[t - 160] = l2[t - 160];
    }
    // init c = ones
    if (t >= 240 && t < 240 + MP1) {
        int j = t - 240;
        c2[(j / 10) * 12 + j % 10] = 1.0f;
    }
    __syncthreads();

    const int a = t >> 3, p = t & 7;

    // Build S row (s) and S^T row (st) fragments + keep c-vector costs (cc)
    float s[10], st[10], cc[10];
    #pragma unroll
    for (int q = 0; q < 10; ++q) {
        int j = p * 10 + q;
        float cij, cji;
        if (a < N1 && j < N1)           cij = nodeC[lab1[a] * NB_LABELS + lab2[j]];
        else if (a == N1 && j == N1)    cij = 0.f;
        else                            cij = NODE_INS_DEL;
        if (j < N1 && a < N1)           cji = nodeC[lab1[j] * NB_LABELS + lab2[a]];
        else if (j == N1 && a == N1)    cji = 0.f;
        else                            cji = NODE_INS_DEL;
        cc[q] = cij;
        s[q]  = __expf(-0.5f * cij);
        st[q] = __expf(-0.5f * cji);
    }

    float ri = 0.f;
    for (int it = 0; it < SINKHORN_ITERS; ++it) {
        // r = 1 / (S c)
        float4 cA = *(const float4*)&c2[p * 12];
        float4 cB = *(const float4*)&c2[p * 12 + 4];
        float2 cC = *(const float2*)&c2[p * 12 + 8];
        float y = s[0] * cA.x + s[1] * cA.y + s[2] * cA.z + s[3] * cA.w
                + s[4] * cB.x + s[5] * cB.y + s[6] * cB.z + s[7] * cB.w
                + s[8] * cC.x + s[9] * cC.y;
        y += __shfl_xor(y, 1, 64);
        y += __shfl_xor(y, 2, 64);
        y += __shfl_xor(y, 4, 64);
        ri = 1.0f / y;
        if (p == 0) r2[(a / 10) * 12 + a % 10] = ri;
        __syncthreads();
        // c = 1 / (S^T r)
        float4 rA = *(const float4*)&r2[p * 12];
        float4 rB = *(const float4*)&r2[p * 12 + 4];
        float2 rC = *(const float2*)&r2[p * 12 + 8];
        float z = st[0] * rA.x + st[1] * rA.y + st[2] * rA.z + st[3] * rA.w
                + st[4] * rB.x + st[5] * rB.y + st[6] * rB.z + st[7] * rB.w
                + st[8] * rC.x + st[9] * rC.y;
        z += __shfl_xor(z, 1, 64);
        z += __shfl_xor(z, 2, 64);
        z += __shfl_xor(z, 4, 64);
        float ci = 1.0f / z;
        if (p == 0) c2[(a / 10) * 12 + a % 10] = ci;
        __syncthreads();
    }

    // v[a][10p+q] = ri * s[q] * c_q ; cv = sum c .* v
    float4 cA = *(const float4*)&c2[p * 12];
    float4 cB = *(const float4*)&c2[p * 12 + 4];
    float2 cC = *(const float2*)&c2[p * 12 + 8];
    float cq[10] = {cA.x, cA.y, cA.z, cA.w, cB.x, cB.y, cB.z, cB.w, cC.x, cC.y};
    float vv[10];
    float cvloc = 0.f;
    #pragma unroll
    for (int q = 0; q < 10; ++q) {
        vv[q] = ri * s[q] * cq[q];
        cvloc = fmaf(cc[q], vv[q], cvloc);
    }
    float* vout = &ws[WS_V + a * MP1 + p * 10];
    #pragma unroll
    for (int q = 0; q < 10; q += 2)
        *(float2*)&vout[q] = make_float2(vv[q], vv[q + 1]);

    if (t < 25) ws[WS_T + t] = T5[t];

    // block reduction of cvloc (10 waves)
    #pragma unroll
    for (int off = 32; off > 0; off >>= 1) cvloc += __shfl_down(cvloc, off, 64);
    if ((t & 63) == 0) red[t >> 6] = cvloc;
    __syncthreads();
    if (t == 0) {
        float sum = 0.f;
        #pragma unroll
        for (int w = 0; w < 10; ++w) sum += red[w];
        ws[WS_CV] = sum;
        ((int*)ws)[WS_CNT] = 0;
    }
}

// ---------------------------------------------------------------------------
// K2: quadratic form, factored per j (unchanged, proven correct), plus the
// fused final reduction: last-arriving block deterministically sums the 80
// partials and writes ged = cv + 0.5 * sum_j partial_j.
// ---------------------------------------------------------------------------
__global__ __launch_bounds__(256) void k_quad(
    const int* __restrict__ Ag1, const int* __restrict__ Ag2,
    float* __restrict__ ws, float* __restrict__ dout)
{
    __shared__ float T5[25];
    __shared__ int   a1col[MP1];
    __shared__ float Gp[3][5][MP1];
    __shared__ float G[5][MP1];
    __shared__ float Up[3][MP1];
    __shared__ float wred[256];
    __shared__ int   amlast;
    __shared__ float finred[2];

    const float* v = ws + WS_V;
    const int j = blockIdx.x;     // 0..79
    const int t = threadIdx.x;

    if (t < 25) T5[t] = ws[WS_T + t];
    if (t < MP1) a1col[t] = (t < N1 && j < N1) ? Ag1[t * N1 + j] : 0;
    __syncthreads();

    // build G[b][l] (i-range split 3 ways over 240 threads)
    if (t < 240) {
        int l = t % MP1, p = t / MP1;
        int i0 = p * 27, i1 = min(i0 + 27, MP1);
        float g0 = 0, g1 = 0, g2 = 0, g3 = 0, g4 = 0;
        for (int i = i0; i < i1; ++i) {
            int a1 = a1col[i];
            float vvl = v[i * MP1 + l];
            const float* Tr = &T5[a1 * 5];
            g0 = fmaf(Tr[0], vvl, g0);
            g1 = fmaf(Tr[1], vvl, g1);
            g2 = fmaf(Tr[2], vvl, g2);
            g3 = fmaf(Tr[3], vvl, g3);
            g4 = fmaf(Tr[4], vvl, g4);
        }
        Gp[p][0][l] = g0; Gp[p][1][l] = g1; Gp[p][2][l] = g2;
        Gp[p][3][l] = g3; Gp[p][4][l] = g4;
    }
    __syncthreads();
    if (t < MP1) {
        #pragma unroll
        for (int b = 0; b < 5; ++b)
            G[b][t] = Gp[0][b][t] + Gp[1][b][t] + Gp[2][b][t];
    }
    __syncthreads();

    // u_{j,k} = sum_l G[a2(k,l)][l]   (l-range split 3 ways)
    if (t < 240) {
        int k = t % MP1, p = t / MP1;
        int l0 = p * 27, l1e = min(l0 + 27, MP1);
        float sacc = 0.f;
        for (int l = l0; l < l1e; ++l) {
            int a2 = (k < N1 && l < N1) ? Ag2[k * N1 + l] : 0;
            sacc += G[a2][l];
        }
        Up[p][k] = sacc;
    }
    __syncthreads();

    float w = 0.f;
    if (t < MP1) {
        int k = t;
        float u = Up[0][k] + Up[1][k] + Up[2][k];
        int a1d = (j < N1) ? Ag1[j * N1 + j] : 0;
        int a2d = (k < N1) ? Ag2[k * N1 + k] : 0;
        float vr = v[j * MP1 + k];
        u -= T5[a1d * 5 + a2d] * vr;    // remove diagonal (r==s) term
        w = vr * u;
    }
    wred[t] = w;
    __syncthreads();
    #pragma unroll
    for (int s2 = 128; s2 > 0; s2 >>= 1) {
        if (t < s2) wred[t] += wred[t + s2];
        __syncthreads();
    }

    // publish partial, count arrivals; last block does the final reduce
    if (t == 0) {
        ws[WS_PJ + j] = wred[0];
        __threadfence();
        int old = atomicAdd((int*)ws + WS_CNT, 1);
        amlast = (old == MP1 - 1) ? 1 : 0;
    }
    __syncthreads();
    if (amlast) {
        __threadfence();
        float val = (t < MP1) ? ws[WS_PJ + t] : 0.f;
        #pragma unroll
        for (int off = 32; off > 0; off >>= 1) val += __shfl_down(val, off, 64);
        if (t == 0)  finred[0] = val;
        if (t == 64) finred[1] = val;
    }
    __syncthreads();
    if (amlast && t == 0)
        dout[0] = ws[WS_CV] + 0.5f * (finred[0] + finred[1]);
}

extern "C" void kernel_launch(void* const* d_in, const int* in_sizes, int n_in,
                              void* d_out, int out_size, void* d_ws, size_t ws_size,
                              hipStream_t stream) {
    const int*   Ag1 = (const int*)d_in[0];
    const int*   Ag2 = (const int*)d_in[1];
    const int*   l1  = (const int*)d_in[2];
    const int*   l2  = (const int*)d_in[3];
    const float* nw  = (const float*)d_in[4];
    const float* ew  = (const float*)d_in[5];
    float* out = (float*)d_out;
    float* ws  = (float*)d_ws;

    k1_sinkhorn<<<1, 640, 0, stream>>>(l1, l2, nw, ew, ws);
    k_quad<<<MP1, 256, 0, stream>>>(Ag1, Ag2, ws, out);
}

// Round 3
// 27.636 us; speedup vs baseline: 1.5912x; 1.1881x over previous
//
#include <hip/hip_runtime.h>
#include <hip/hip_bf16.h>

// Problem constants (from reference)
#define NB_LABELS 10
#define NB_EDGE_LABELS 4
#define N1 79
#define MP1 80           // n+1 = m+1 = 80
#define NODE_INS_DEL 0.03f
#define SINKHORN_ITERS 10

// ws layout:
//  int[0]         arrival counter (hipMemsetAsync to 0 each call)
//  float[8..88)   per-j partial sums of v_r * u_r
#define WS_PJ   8

// ---------------------------------------------------------------------------
// Fused kernel, 80 blocks x 640 threads.
// Every block redundantly runs Sinkhorn (scaling-vector form, ~1-2us, fully
// parallel across blocks -> no serial single-block phase, no extra launch),
// keeps v in LDS, then computes the factored quadratic form for j=blockIdx.x:
//   u_{j,k} = sum_l G_j[A2p[k,l]][l],  G_j[b][l] = sum_i T[a1col[i],b] v[i][l]
// Partial_j = sum_k v_{j,k} u_{j,k} (diag term removed). Last-arriving block
// (device atomic counter) reduces the 80 partials deterministically and
// writes ged = c.v + 0.5 * sum_j partial_j.
// ---------------------------------------------------------------------------
__global__ __launch_bounds__(640) void k_fused(
    const int* __restrict__ Ag1, const int* __restrict__ Ag2,
    const int* __restrict__ l1, const int* __restrict__ l2,
    const float* __restrict__ nw, const float* __restrict__ ew,
    float* __restrict__ ws, float* __restrict__ dout)
{
    __shared__ float nodeC[NB_LABELS * NB_LABELS];
    __shared__ float T5[25];
    __shared__ int   lab1[MP1], lab2[MP1];
    __shared__ __align__(16) float c2[8 * 12];   // c vector, padded per p-group
    __shared__ __align__(16) float r2[8 * 12];   // r vector, padded per p-group
    __shared__ float red[10];
    __shared__ float cvs;
    __shared__ float v_lds[MP1 * MP1];            // Sinkhorn result
    __shared__ int   A2p[MP1 * 81];               // padded A2, pitch 81 (bank-safe)
    __shared__ int   a1col[MP1];
    __shared__ float Gp[8][5][MP1];
    __shared__ float G[5 * MP1];
    __shared__ float Up[8][MP1];
    __shared__ float wred[MP1];
    __shared__ int   amlast;

    const int t = threadIdx.x;
    const int j = blockIdx.x;     // 0..79

    // ---- stage inputs: A2 padded into LDS (coalesced), A1 column j, tables
    for (int idx = t; idx < MP1 * MP1; idx += 640) {
        int k = idx / MP1, l = idx % MP1;
        A2p[k * 81 + l] = (k < N1 && l < N1) ? Ag2[k * N1 + l] : 0;
    }
    if (t >= 640 - MP1) {        // threads 560..639
        int i = t - (640 - MP1);
        a1col[i] = (i < N1 && j < N1) ? Ag1[i * N1 + j] : 0;
    }
    // node_costs: symmetric from upper-tri vec (triu_indices order), diag 0
    if (t < NB_LABELS * NB_LABELS) {
        int i = t / NB_LABELS, jj = t % NB_LABELS;
        float val = 0.f;
        if (i != jj) {
            int a = min(i, jj), b = max(i, jj);
            int p = a * (NB_LABELS - 1) - a * (a - 1) / 2 + (b - a - 1);
            val = fmaxf(nw[p], 0.f);
        }
        nodeC[t] = val;
    }
    // edge table 5x5
    if (t >= 128 && t < 153) {
        int q = t - 128;
        int a = q / 5, b = q % 5;
        float val;
        if (a == 0 && b == 0)       val = 0.f;
        else if (a == 0 || b == 0)  val = fmaxf(ew[NB_EDGE_LABELS * (NB_EDGE_LABELS - 1) / 2], 0.f);
        else if (a == b)            val = 0.f;
        else {
            int x = min(a, b) - 1, y = max(a, b) - 1;
            int p = x * (NB_EDGE_LABELS - 1) - x * (x - 1) / 2 + (y - x - 1);
            val = fmaxf(ew[p], 0.f);
        }
        T5[q] = val;
    }
    if (t >= 160 && t < 160 + N1) {
        lab1[t - 160] = l1[t - 160];
        lab2[t - 160] = l2[t - 160];
    }
    if (t >= 240 && t < 240 + MP1) {
        int jj = t - 240;
        c2[(jj / 10) * 12 + jj % 10] = 1.0f;   // c = ones
    }
    __syncthreads();

    // ---- Sinkhorn in scaling form: thread (a,p) holds S[a][10p+q], S^T[a][10p+q]
    const int a = t >> 3, p = t & 7;
    float s[10], st[10], cc[10];
    #pragma unroll
    for (int q = 0; q < 10; ++q) {
        int jj = p * 10 + q;
        float cij, cji;
        if (a < N1 && jj < N1)          cij = nodeC[lab1[a] * NB_LABELS + lab2[jj]];
        else if (a == N1 && jj == N1)   cij = 0.f;
        else                            cij = NODE_INS_DEL;
        if (jj < N1 && a < N1)          cji = nodeC[lab1[jj] * NB_LABELS + lab2[a]];
        else if (jj == N1 && a == N1)   cji = 0.f;
        else                            cji = NODE_INS_DEL;
        cc[q] = cij;
        s[q]  = __expf(-0.5f * cij);
        st[q] = __expf(-0.5f * cji);
    }

    float ri = 0.f;
    for (int it = 0; it < SINKHORN_ITERS; ++it) {
        // r = 1 / (S c)
        float4 cA = *(const float4*)&c2[p * 12];
        float4 cB = *(const float4*)&c2[p * 12 + 4];
        float2 cC = *(const float2*)&c2[p * 12 + 8];
        float y = s[0] * cA.x + s[1] * cA.y + s[2] * cA.z + s[3] * cA.w
                + s[4] * cB.x + s[5] * cB.y + s[6] * cB.z + s[7] * cB.w
                + s[8] * cC.x + s[9] * cC.y;
        y += __shfl_xor(y, 1, 64);
        y += __shfl_xor(y, 2, 64);
        y += __shfl_xor(y, 4, 64);
        ri = 1.0f / y;
        if (p == 0) r2[(a / 10) * 12 + a % 10] = ri;
        __syncthreads();
        // c = 1 / (S^T r)
        float4 rA = *(const float4*)&r2[p * 12];
        float4 rB = *(const float4*)&r2[p * 12 + 4];
        float2 rC = *(const float2*)&r2[p * 12 + 8];
        float z = st[0] * rA.x + st[1] * rA.y + st[2] * rA.z + st[3] * rA.w
                + st[4] * rB.x + st[5] * rB.y + st[6] * rB.z + st[7] * rB.w
                + st[8] * rC.x + st[9] * rC.y;
        z += __shfl_xor(z, 1, 64);
        z += __shfl_xor(z, 2, 64);
        z += __shfl_xor(z, 4, 64);
        float ci = 1.0f / z;
        if (p == 0) c2[(a / 10) * 12 + a % 10] = ci;
        __syncthreads();
    }

    // ---- v into LDS; cv = c.v reduced per block (identical in all blocks)
    {
        float4 cA = *(const float4*)&c2[p * 12];
        float4 cB = *(const float4*)&c2[p * 12 + 4];
        float2 cC = *(const float2*)&c2[p * 12 + 8];
        float cq[10] = {cA.x, cA.y, cA.z, cA.w, cB.x, cB.y, cB.z, cB.w, cC.x, cC.y};
        float cvloc = 0.f;
        float* vout = &v_lds[a * MP1 + p * 10];
        #pragma unroll
        for (int q = 0; q < 10; ++q) {
            float vv = ri * s[q] * cq[q];
            vout[q] = vv;
            cvloc = fmaf(cc[q], vv, cvloc);
        }
        #pragma unroll
        for (int off = 32; off > 0; off >>= 1) cvloc += __shfl_down(cvloc, off, 64);
        if ((t & 63) == 0) red[t >> 6] = cvloc;
    }
    __syncthreads();   // publishes v_lds + red
    if (t == 0) {
        float sum = 0.f;
        #pragma unroll
        for (int w = 0; w < 10; ++w) sum += red[w];
        cvs = sum;
    }

    // ---- G_j[b][l] = sum_i T[a1col[i],b] * v[i][l], i split 8 ways
    {
        int l = t % MP1, pp = t / MP1;     // pp 0..7
        int i0 = pp * 10;
        float g0 = 0, g1 = 0, g2 = 0, g3 = 0, g4 = 0;
        #pragma unroll
        for (int q = 0; q < 10; ++q) {
            int i = i0 + q;
            int a1 = a1col[i];
            float vvl = v_lds[i * MP1 + l];
            const float* Tr = &T5[a1 * 5];
            g0 = fmaf(Tr[0], vvl, g0);
            g1 = fmaf(Tr[1], vvl, g1);
            g2 = fmaf(Tr[2], vvl, g2);
            g3 = fmaf(Tr[3], vvl, g3);
            g4 = fmaf(Tr[4], vvl, g4);
        }
        Gp[pp][0][l] = g0; Gp[pp][1][l] = g1; Gp[pp][2][l] = g2;
        Gp[pp][3][l] = g3; Gp[pp][4][l] = g4;
    }
    __syncthreads();   // publishes Gp + cvs
    if (t < 400) {
        int b = t / MP1, l = t % MP1;
        float g = 0.f;
        #pragma unroll
        for (int pp = 0; pp < 8; ++pp) g += Gp[pp][b][l];
        G[b * MP1 + l] = g;
    }
    __syncthreads();

    // ---- u_{j,k} = sum_l G[A2p[k][l]][l], l split 8 ways
    {
        int k = t % MP1, pp = t / MP1;
        int l0 = pp * 10;
        float sacc = 0.f;
        #pragma unroll
        for (int q = 0; q < 10; ++q) {
            int l = l0 + q;
            int a2 = A2p[k * 81 + l];
            sacc += G[a2 * MP1 + l];
        }
        Up[pp][k] = sacc;
    }
    __syncthreads();

    // ---- w_k = v_{j,k} * (u_k - diag term); wred
    if (t < MP1) {
        int k = t;
        float u = 0.f;
        #pragma unroll
        for (int pp = 0; pp < 8; ++pp) u += Up[pp][k];
        int a1d = (j < N1) ? Ag1[j * MP1] : 0;       // j*N1+j == j*80
        int a2d = A2p[k * 81 + k];
        float vr = v_lds[j * MP1 + k];
        u -= T5[a1d * 5 + a2d] * vr;                 // remove r==s diagonal term
        wred[t] = vr * u;
    }
    __syncthreads();

    // ---- per-block partial (deterministic 2-wave shfl reduce of 80 values)
    if (t < 64) {
        float val = wred[t] + ((t < 16) ? wred[64 + t] : 0.f);
        #pragma unroll
        for (int off = 32; off > 0; off >>= 1) val += __shfl_down(val, off, 64);
        if (t == 0) {
            ws[WS_PJ + j] = val;
            __threadfence();
            int old = atomicAdd((int*)ws, 1);
            amlast = (old == MP1 - 1) ? 1 : 0;
        }
    }
    __syncthreads();

    // ---- last-arriving block: final deterministic reduce + output
    if (amlast) {
        __threadfence();
        if (t < 64) {
            float val = ws[WS_PJ + t] + ((t < 16) ? ws[WS_PJ + 64 + t] : 0.f);
            #pragma unroll
            for (int off = 32; off > 0; off >>= 1) val += __shfl_down(val, off, 64);
            if (t == 0) dout[0] = cvs + 0.5f * val;
        }
    }
}

extern "C" void kernel_launch(void* const* d_in, const int* in_sizes, int n_in,
                              void* d_out, int out_size, void* d_ws, size_t ws_size,
                              hipStream_t stream) {
    const int*   Ag1 = (const int*)d_in[0];
    const int*   Ag2 = (const int*)d_in[1];
    const int*   l1  = (const int*)d_in[2];
    const int*   l2  = (const int*)d_in[3];
    const float* nw  = (const float*)d_in[4];
    const float* ew  = (const float*)d_in[5];
    float* out = (float*)d_out;
    float* ws  = (float*)d_ws;

    // zero the arrival counter (4 bytes) — graph-capture-legal async memset
    hipMemsetAsync(d_ws, 0, 4, stream);
    k_fused<<<MP1, 640, 0, stream>>>(Ag1, Ag2, l1, l2, nw, ew, ws, out);
}

// Round 4
// 22.434 us; speedup vs baseline: 1.9602x; 1.2319x over previous
//
#include <hip/hip_runtime.h>
#include <hip/hip_bf16.h>

// Problem constants (from reference)
#define NB_LABELS 10
#define NB_EDGE_LABELS 4
#define N1 79
#define MP1 80           // n+1 = m+1 = 80
#define NODE_INS_DEL 0.03f
#define SINKHORN_ITERS 10

// ws layout: float[8..88) = per-j partial sums of v_r * u_r
#define WS_PJ   8

// Arrival counter lives in module .data (zeroed once at module load; the
// harness's 0xAA poison touches only d_out/d_ws). Invariant: g_cnt % 80 == 0
// at every kernel_launch entry — each call's 80 blocks add exactly +80, so
// the invariant self-sustains across the correctness call and all graph
// replays. "Last arrival" = (old % 80 == 79). Same behavior every call.
__device__ int g_cnt = 0;

// ---------------------------------------------------------------------------
// Fused kernel, 80 blocks x 640 threads, single graph node.
// Every block redundantly runs Sinkhorn (scaling-vector form, fully parallel
// across blocks), keeps v in LDS, then computes the factored quadratic form
// for j=blockIdx.x:
//   u_{j,k} = sum_l G_j[A2p[k,l]][l],  G_j[b][l] = sum_i T[a1col[i],b] v[i][l]
// Partial_j = sum_k v_{j,k} u_{j,k} (diag term removed). Last-arriving block
// reduces the 80 partials deterministically and writes
//   ged = c.v + 0.5 * sum_j partial_j.
// ---------------------------------------------------------------------------
__global__ __launch_bounds__(640) void k_fused(
    const int* __restrict__ Ag1, const int* __restrict__ Ag2,
    const int* __restrict__ l1, const int* __restrict__ l2,
    const float* __restrict__ nw, const float* __restrict__ ew,
    float* __restrict__ ws, float* __restrict__ dout)
{
    __shared__ float nodeC[NB_LABELS * NB_LABELS];
    __shared__ float T5[25];
    __shared__ int   lab1[MP1], lab2[MP1];
    __shared__ __align__(16) float c2[8 * 12];   // c vector, padded per p-group
    __shared__ __align__(16) float r2[8 * 12];   // r vector, padded per p-group
    __shared__ float red[10];
    __shared__ float cvs;
    __shared__ float v_lds[MP1 * MP1];            // Sinkhorn result
    __shared__ int   A2p[MP1 * 81];               // padded A2, pitch 81 (bank-safe)
    __shared__ int   a1col[MP1];
    __shared__ float Gp[8][5][MP1];
    __shared__ float G[5 * MP1];
    __shared__ float Up[8][MP1];
    __shared__ float wred[MP1];
    __shared__ int   amlast;

    const int t = threadIdx.x;
    const int j = blockIdx.x;     // 0..79

    // ---- stage inputs: A2 padded into LDS (coalesced), A1 column j, tables
    {
        const int l = t % MP1;          // constant per thread
        const int k0 = t / MP1;         // 0..7, advances by 8 per iter
        #pragma unroll
        for (int it = 0; it < 10; ++it) {
            int k = k0 + it * 8;
            A2p[k * 81 + l] = (k < N1 && l < N1) ? Ag2[k * N1 + l] : 0;
        }
    }
    if (t >= 640 - MP1) {        // threads 560..639
        int i = t - (640 - MP1);
        a1col[i] = (i < N1 && j < N1) ? Ag1[i * N1 + j] : 0;
    }
    // node_costs: symmetric from upper-tri vec (triu_indices order), diag 0
    if (t < NB_LABELS * NB_LABELS) {
        int i = t / NB_LABELS, jj = t % NB_LABELS;
        float val = 0.f;
        if (i != jj) {
            int a = min(i, jj), b = max(i, jj);
            int p = a * (NB_LABELS - 1) - a * (a - 1) / 2 + (b - a - 1);
            val = fmaxf(nw[p], 0.f);
        }
        nodeC[t] = val;
    }
    // edge table 5x5
    if (t >= 128 && t < 153) {
        int q = t - 128;
        int a = q / 5, b = q % 5;
        float val;
        if (a == 0 && b == 0)       val = 0.f;
        else if (a == 0 || b == 0)  val = fmaxf(ew[NB_EDGE_LABELS * (NB_EDGE_LABELS - 1) / 2], 0.f);
        else if (a == b)            val = 0.f;
        else {
            int x = min(a, b) - 1, y = max(a, b) - 1;
            int p = x * (NB_EDGE_LABELS - 1) - x * (x - 1) / 2 + (y - x - 1);
            val = fmaxf(ew[p], 0.f);
        }
        T5[q] = val;
    }
    if (t >= 160 && t < 160 + N1) {
        lab1[t - 160] = l1[t - 160];
        lab2[t - 160] = l2[t - 160];
    }
    if (t >= 240 && t < 240 + MP1) {
        int jj = t - 240;
        c2[(jj / 10) * 12 + jj % 10] = 1.0f;   // c = ones
    }
    __syncthreads();

    // ---- Sinkhorn in scaling form: thread (a,p) holds S[a][10p+q], S^T[a][10p+q]
    const int a = t >> 3, p = t & 7;
    float s[10], st[10], cc[10];
    #pragma unroll
    for (int q = 0; q < 10; ++q) {
        int jj = p * 10 + q;
        float cij, cji;
        if (a < N1 && jj < N1)          cij = nodeC[lab1[a] * NB_LABELS + lab2[jj]];
        else if (a == N1 && jj == N1)   cij = 0.f;
        else                            cij = NODE_INS_DEL;
        if (jj < N1 && a < N1)          cji = nodeC[lab1[jj] * NB_LABELS + lab2[a]];
        else if (jj == N1 && a == N1)   cji = 0.f;
        else                            cji = NODE_INS_DEL;
        cc[q] = cij;
        s[q]  = __expf(-0.5f * cij);
        st[q] = __expf(-0.5f * cji);
    }

    float ri = 0.f;
    for (int it = 0; it < SINKHORN_ITERS; ++it) {
        // r = 1 / (S c)
        float4 cA = *(const float4*)&c2[p * 12];
        float4 cB = *(const float4*)&c2[p * 12 + 4];
        float2 cC = *(const float2*)&c2[p * 12 + 8];
        float y = s[0] * cA.x + s[1] * cA.y + s[2] * cA.z + s[3] * cA.w
                + s[4] * cB.x + s[5] * cB.y + s[6] * cB.z + s[7] * cB.w
                + s[8] * cC.x + s[9] * cC.y;
        y += __shfl_xor(y, 1, 64);
        y += __shfl_xor(y, 2, 64);
        y += __shfl_xor(y, 4, 64);
        ri = 1.0f / y;
        if (p == 0) r2[(a / 10) * 12 + a % 10] = ri;
        __syncthreads();
        // c = 1 / (S^T r)
        float4 rA = *(const float4*)&r2[p * 12];
        float4 rB = *(const float4*)&r2[p * 12 + 4];
        float2 rC = *(const float2*)&r2[p * 12 + 8];
        float z = st[0] * rA.x + st[1] * rA.y + st[2] * rA.z + st[3] * rA.w
                + st[4] * rB.x + st[5] * rB.y + st[6] * rB.z + st[7] * rB.w
                + st[8] * rC.x + st[9] * rC.y;
        z += __shfl_xor(z, 1, 64);
        z += __shfl_xor(z, 2, 64);
        z += __shfl_xor(z, 4, 64);
        float ci = 1.0f / z;
        if (p == 0) c2[(a / 10) * 12 + a % 10] = ci;
        __syncthreads();
    }

    // ---- v into LDS; cv = c.v reduced per block (identical in all blocks)
    {
        float4 cA = *(const float4*)&c2[p * 12];
        float4 cB = *(const float4*)&c2[p * 12 + 4];
        float2 cC = *(const float2*)&c2[p * 12 + 8];
        float cq[10] = {cA.x, cA.y, cA.z, cA.w, cB.x, cB.y, cB.z, cB.w, cC.x, cC.y};
        float cvloc = 0.f;
        float* vout = &v_lds[a * MP1 + p * 10];
        #pragma unroll
        for (int q = 0; q < 10; ++q) {
            float vv = ri * s[q] * cq[q];
            vout[q] = vv;
            cvloc = fmaf(cc[q], vv, cvloc);
        }
        #pragma unroll
        for (int off = 32; off > 0; off >>= 1) cvloc += __shfl_down(cvloc, off, 64);
        if ((t & 63) == 0) red[t >> 6] = cvloc;
    }
    __syncthreads();   // publishes v_lds + red
    if (t == 0) {
        float sum = 0.f;
        #pragma unroll
        for (int w = 0; w < 10; ++w) sum += red[w];
        cvs = sum;
    }

    // ---- G_j[b][l] = sum_i T[a1col[i],b] * v[i][l], i split 8 ways
    {
        int l = t % MP1, pp = t / MP1;     // pp 0..7
        int i0 = pp * 10;
        float g0 = 0, g1 = 0, g2 = 0, g3 = 0, g4 = 0;
        #pragma unroll
        for (int q = 0; q < 10; ++q) {
            int i = i0 + q;
            int a1 = a1col[i];
            float vvl = v_lds[i * MP1 + l];
            const float* Tr = &T5[a1 * 5];
            g0 = fmaf(Tr[0], vvl, g0);
            g1 = fmaf(Tr[1], vvl, g1);
            g2 = fmaf(Tr[2], vvl, g2);
            g3 = fmaf(Tr[3], vvl, g3);
            g4 = fmaf(Tr[4], vvl, g4);
        }
        Gp[pp][0][l] = g0; Gp[pp][1][l] = g1; Gp[pp][2][l] = g2;
        Gp[pp][3][l] = g3; Gp[pp][4][l] = g4;
    }
    __syncthreads();   // publishes Gp + cvs
    if (t < 400) {
        int b = t / MP1, l = t % MP1;
        float g = 0.f;
        #pragma unroll
        for (int pp = 0; pp < 8; ++pp) g += Gp[pp][b][l];
        G[b * MP1 + l] = g;
    }
    __syncthreads();

    // ---- u_{j,k} = sum_l G[A2p[k][l]][l], l split 8 ways
    {
        int k = t % MP1, pp = t / MP1;
        int l0 = pp * 10;
        float sacc = 0.f;
        #pragma unroll
        for (int q = 0; q < 10; ++q) {
            int l = l0 + q;
            int a2 = A2p[k * 81 + l];
            sacc += G[a2 * MP1 + l];
        }
        Up[pp][k] = sacc;
    }
    __syncthreads();

    // ---- w_k = v_{j,k} * (u_k - diag term)
    if (t < MP1) {
        int k = t;
        float u = 0.f;
        #pragma unroll
        for (int pp = 0; pp < 8; ++pp) u += Up[pp][k];
        int a1d = a1col[j];                          // A1[j][j] (0 for j==N1)
        int a2d = A2p[k * 81 + k];
        float vr = v_lds[j * MP1 + k];
        u -= T5[a1d * 5 + a2d] * vr;                 // remove r==s diagonal term
        wred[t] = vr * u;
    }
    __syncthreads();

    // ---- per-block partial (deterministic 2-wave shfl reduce of 80 values)
    if (t < 64) {
        float val = wred[t] + ((t < 16) ? wred[64 + t] : 0.f);
        #pragma unroll
        for (int off = 32; off > 0; off >>= 1) val += __shfl_down(val, off, 64);
        if (t == 0) {
            ws[WS_PJ + j] = val;
            __threadfence();
            int old = atomicAdd(&g_cnt, 1);
            amlast = ((old % MP1) == MP1 - 1) ? 1 : 0;
        }
    }
    __syncthreads();

    // ---- last-arriving block: final deterministic reduce + output
    if (amlast) {
        __threadfence();
        if (t < 64) {
            float val = ws[WS_PJ + t] + ((t < 16) ? ws[WS_PJ + 64 + t] : 0.f);
            #pragma unroll
            for (int off = 32; off > 0; off >>= 1) val += __shfl_down(val, off, 64);
            if (t == 0) dout[0] = cvs + 0.5f * val;
        }
    }
}

extern "C" void kernel_launch(void* const* d_in, const int* in_sizes, int n_in,
                              void* d_out, int out_size, void* d_ws, size_t ws_size,
                              hipStream_t stream) {
    const int*   Ag1 = (const int*)d_in[0];
    const int*   Ag2 = (const int*)d_in[1];
    const int*   l1  = (const int*)d_in[2];
    const int*   l2  = (const int*)d_in[3];
    const float* nw  = (const float*)d_in[4];
    const float* ew  = (const float*)d_in[5];
    float* out = (float*)d_out;
    float* ws  = (float*)d_ws;

    k_fused<<<MP1, 640, 0, stream>>>(Ag1, Ag2, l1, l2, nw, ew, ws, out);
}

// Round 5
// 15.226 us; speedup vs baseline: 2.8882x; 1.4734x over previous
//
#include <hip/hip_runtime.h>
#include <hip/hip_bf16.h>

// Problem constants (from reference)
#define NL 10            // node label alphabet
#define NE 4             // edge label alphabet
#define N1 79
#define PAD 10           // pad pseudo-label index
#define NLP 11           // NL + pad
#define NODE_INS_DEL 0.03f
#define SINK_ITERS 10

// ---------------------------------------------------------------------------
// Label-space GED. Key fact: S[i][j] = exp(-0.5*nodeC[lab1[i]][lab2[j]]) has
// only 11 distinct row/col types (10 labels + pad row/col). So:
//  * Sinkhorn collapses to 11-dim recurrences with label counts:
//      y[X] = sum_M E[X][M]*cnt2e[M]*gam[M]; rho = 1/y  (and symmetrically)
//  * v[i][j] = V[L1p[i]][L2p[j]],  V[P][S] = rho[P]*E_ext[P][S]*gam[S]
//  * Q_full  = sum_{a,b} T[a][b] * <M1[a], V*M2[b]*V^T>  where
//      M1[a][P][R] = #{(i,j): A1p[i,j]=a, L1p[j]=P, L1p[i]=R}   (note j->P!)
//      M2[b][S][T] = #{(k,l): A2p[k,l]=b, L2p[k]=S, L2p[l]=T}
//  * Diag = sum V[P][S]^2 * (N1d[.][P] T N2d[.][S]),  N*d = diagonal hists
//  * cv   = sum cnt1e[P]*cnt2e[S]*Cc[P][S]*V[P][S]
//  ged = cv + 0.5*(Q_full - Diag)
// One block, 512 threads: wave 0 does Sinkhorn while waves 1-7 histogram.
// ---------------------------------------------------------------------------
__global__ __launch_bounds__(512) void k_ged(
    const int* __restrict__ Ag1, const int* __restrict__ Ag2,
    const int* __restrict__ l1, const int* __restrict__ l2,
    const float* __restrict__ nw, const float* __restrict__ ew,
    float* __restrict__ dout)
{
    __shared__ float E_ext[121];        // exp(-0.5*cost) in label space (symmetric)
    __shared__ float Cc[121];           // node-cost in label space (with pad borders)
    __shared__ float T5[25];            // edge-pair cost table
    __shared__ float Vm[121];           // V = diag(rho) E_ext diag(gam)
    __shared__ int   lab1[N1], lab2[N1];
    __shared__ int   cnt1[NLP], cnt2[NLP];
    __shared__ int   h1[8][605], h2[8][605];   // privatized M1/M2 histograms
    __shared__ int   nd1[55], nd2[55];         // diagonal histograms [a][P]
    __shared__ float M1f[605], M2f[605];
    __shared__ float N1f[55], N2f[55];
    __shared__ float rho[NLP], gam[NLP];
    __shared__ float Ub[605], Yb[605];
    __shared__ float redL[8];

    const int t = threadIdx.x;

    // ---------------- A0: zero, load labels, build tables ----------------
    {
        int* hz1 = &h1[0][0];
        int* hz2 = &h2[0][0];
        for (int i = t; i < 8 * 605; i += 512) { hz1[i] = 0; hz2[i] = 0; }
    }
    if (t < 55)  nd1[t] = 0;
    if (t >= 55 && t < 110) nd2[t - 55] = 0;
    if (t >= 158 && t < 168) cnt1[t - 158] = 0;
    if (t >= 168 && t < 178) cnt2[t - 168] = 0;
    if (t == 178) cnt1[PAD] = 1;
    if (t == 179) cnt2[PAD] = 1;
    if (t < N1)               lab1[t] = l1[t];
    if (t >= 79 && t < 158)   lab2[t - 79] = l2[t - 79];
    if (t >= 192 && t < 313) {          // E_ext + Cc (label space, incl pad)
        int q = t - 192, P = q / 11, S = q - P * 11;
        float cost;
        if (P < NL && S < NL) {
            if (P == S) cost = 0.f;
            else {
                int x = min(P, S), y = max(P, S);
                int pidx = x * (NL - 1) - x * (x - 1) / 2 + (y - x - 1);
                cost = fmaxf(nw[pidx], 0.f);
            }
        } else if (P == PAD && S == PAD) cost = 0.f;
        else cost = NODE_INS_DEL;
        Cc[q] = cost;
        E_ext[q] = __expf(-0.5f * cost);
    }
    if (t >= 320 && t < 345) {          // edge table 5x5
        int q = t - 320, a = q / 5, b = q - a * 5;
        float val;
        if (a == 0 && b == 0)       val = 0.f;
        else if (a == 0 || b == 0)  val = fmaxf(ew[NE * (NE - 1) / 2], 0.f);
        else if (a == b)            val = 0.f;
        else {
            int x = min(a, b) - 1, y = max(a, b) - 1;
            int p = x * (NE - 1) - x * (x - 1) / 2 + (y - x - 1);
            val = fmaxf(ew[p], 0.f);
        }
        T5[q] = val;
    }
    __syncthreads();

    // ---------------- A1: label counts ----------------
    if (t < N1)               atomicAdd(&cnt1[lab1[t]], 1);
    if (t >= 79 && t < 158)   atomicAdd(&cnt2[lab2[t - 79]], 1);
    __syncthreads();

    // ---------------- A2: Sinkhorn (wave 0) || histograms (waves 1-7) ----
    if (t < 64) {
        // Label-space Sinkhorn: lane = X*4+q; lane group of 4 computes the
        // 11-term dot for label X (3 terms per lane), xor-reduced in-group.
        const int X = t >> 2, q = t & 3;
        const bool valid = (X < NLP);
        float ec2[3], ec1[3];
        #pragma unroll
        for (int k = 0; k < 3; ++k) {
            int M = 3 * q + k;
            if (valid && M < NLP) {
                float e = E_ext[X * 11 + M];
                ec2[k] = e * (float)cnt2[M];
                ec1[k] = e * (float)cnt1[M];
            } else { ec2[k] = 0.f; ec1[k] = 0.f; }
        }
        const int s0 = 4 * (3 * q + 0);
        const int s1 = 4 * (3 * q + 1);
        const int s2 = (3 * q + 2 < NLP) ? 4 * (3 * q + 2) : 0;  // clamp: weight is 0
        float gX = 1.0f, rX = 1.0f;
        for (int it = 0; it < SINK_ITERS; ++it) {
            float g0 = __shfl(gX, s0, 64);
            float g1 = __shfl(gX, s1, 64);
            float g2 = __shfl(gX, s2, 64);
            float y = ec2[0] * g0 + ec2[1] * g1 + ec2[2] * g2;
            y += __shfl_xor(y, 1, 64);
            y += __shfl_xor(y, 2, 64);
            rX = valid ? (1.0f / y) : 0.f;
            float r0 = __shfl(rX, s0, 64);
            float r1 = __shfl(rX, s1, 64);
            float r2 = __shfl(rX, s2, 64);
            float z = ec1[0] * r0 + ec1[1] * r1 + ec1[2] * r2;
            z += __shfl_xor(z, 1, 64);
            z += __shfl_xor(z, 2, 64);
            gX = valid ? (1.0f / z) : 0.f;
        }
        if (valid && q == 0) { rho[X] = rX; gam[X] = gX; }
    } else if (t < 288) {
        // graph-1 interior histogram: M1[a][lab1[j]][lab1[i]]
        int* hp = h1[t >> 6];
        // pad borders (i=79 row / j=79 col of the padded 80x80):
        if (t >= 64 && t < 75)   atomicAdd(&h1[1][(t - 64) * 11 + 10], cnt1[t - 64]); // P=0..10 (P=10 -> corner, cnt1e=1)
        if (t >= 80 && t < 90)   atomicAdd(&h1[1][110 + (t - 80)], cnt1[t - 80]);     // R=0..9
        if (t >= 96 && t < 107)  atomicAdd(&h2[1][(t - 96) * 11 + 10], cnt2[t - 96]);
        if (t >= 112 && t < 122) atomicAdd(&h2[1][110 + (t - 112)], cnt2[t - 112]);
        // diagonal histograms
        if (t >= 64 && t < 64 + N1) {
            int j = t - 64;
            atomicAdd(&nd1[Ag1[j * 80] * 11 + lab1[j]], 1);   // A1[j][j] = Ag1[j*79+j]
        }
        if (t >= 144 && t < 144 + N1) {
            int k = t - 144;
            atomicAdd(&nd2[Ag2[k * 80] * 11 + lab2[k]], 1);
        }
        if (t == 224) nd1[10] = 1;   // pad diag (j=79): a=0, P=PAD
        if (t == 225) nd2[10] = 1;
        for (int n = t - 64; n < N1 * N1; n += 224) {
            int a = Ag1[n];
            int i = n / N1, j = n - i * N1;
            atomicAdd(&hp[a * 121 + lab1[j] * 11 + lab1[i]], 1);
        }
    } else {
        // graph-2 interior histogram: M2[b][lab2[k]][lab2[l]]
        int* hp = h2[t >> 6];
        for (int n = t - 288; n < N1 * N1; n += 224) {
            int b = Ag2[n];
            int k = n / N1, l = n - k * N1;
            atomicAdd(&hp[b * 121 + lab2[k] * 11 + lab2[l]], 1);
        }
    }
    __syncthreads();

    // ---------------- B: reduce histogram copies; build V ----------------
    for (int i = t; i < 605; i += 512) {
        int s1v = 0, s2v = 0;
        #pragma unroll
        for (int w = 0; w < 8; ++w) { s1v += h1[w][i]; s2v += h2[w][i]; }
        M1f[i] = (float)s1v;
        M2f[i] = (float)s2v;
    }
    if (t < 55) { N1f[t] = (float)nd1[t]; N2f[t] = (float)nd2[t]; }
    if (t >= 64 && t < 185) {
        int q = t - 64;
        Vm[q] = rho[q / 11] * E_ext[q] * gam[q % 11];
    }
    __syncthreads();

    // ---------------- C: Ub[b][S][R] = sum_T M2[b][S][T] * V[R][T] -------
    for (int idx = t; idx < 605; idx += 512) {
        int b = idx / 121, r = idx - b * 121;
        int S = r / 11, R = r - S * 11;
        const float* m2 = &M2f[b * 121 + S * 11];
        const float* vr = &Vm[R * 11];
        float s = 0.f;
        #pragma unroll
        for (int T = 0; T < 11; ++T) s = fmaf(m2[T], vr[T], s);
        Ub[idx] = s;
    }
    __syncthreads();

    // ---------------- D: Yb[b][P][R] = sum_S V[P][S] * Ub[b][S][R] -------
    for (int idx = t; idx < 605; idx += 512) {
        int b = idx / 121, r = idx - b * 121;
        int P = r / 11, R = r - P * 11;
        float s = 0.f;
        #pragma unroll
        for (int S = 0; S < 11; ++S) s = fmaf(Vm[P * 11 + S], Ub[b * 121 + S * 11 + R], s);
        Yb[idx] = s;
    }
    __syncthreads();

    // ---------------- E: final contraction + reduce ----------------------
    float part = 0.f;
    if (t < 121) {
        int P = t / 11, R = t - P * 11;
        // Q_full part: sum_a M1[a][P][R] * sum_b T[a][b] Yb[b][P][R]
        float qf = 0.f;
        #pragma unroll
        for (int a = 0; a < 5; ++a) {
            float sa = 0.f;
            #pragma unroll
            for (int b = 0; b < 5; ++b) sa = fmaf(T5[a * 5 + b], Yb[b * 121 + t], sa);
            qf = fmaf(M1f[a * 121 + t], sa, qf);
        }
        // Diag part: V^2 * sum_{a,b} N1d[a][P] T[a][b] N2d[b][R]
        float sd = 0.f;
        #pragma unroll
        for (int a = 0; a < 5; ++a) {
            float sb = 0.f;
            #pragma unroll
            for (int b = 0; b < 5; ++b) sb = fmaf(T5[a * 5 + b], N2f[b * 11 + R], sb);
            sd = fmaf(N1f[a * 11 + P], sb, sd);
        }
        float vv = Vm[t];
        float dpart = vv * vv * sd;
        // cv part
        float cvp = (float)cnt1[P] * (float)cnt2[R] * Cc[t] * vv;
        part = cvp + 0.5f * (qf - dpart);
    }
    // block reduction (only waves 0,1 hold nonzero)
    #pragma unroll
    for (int off = 1; off < 64; off <<= 1) part += __shfl_xor(part, off, 64);
    if ((t & 63) == 0) redL[t >> 6] = part;
    __syncthreads();
    if (t == 0) {
        float s = 0.f;
        #pragma unroll
        for (int w = 0; w < 8; ++w) s += redL[w];
        dout[0] = s;
    }
}

extern "C" void kernel_launch(void* const* d_in, const int* in_sizes, int n_in,
                              void* d_out, int out_size, void* d_ws, size_t ws_size,
                              hipStream_t stream) {
    const int*   Ag1 = (const int*)d_in[0];
    const int*   Ag2 = (const int*)d_in[1];
    const int*   l1  = (const int*)d_in[2];
    const int*   l2  = (const int*)d_in[3];
    const float* nw  = (const float*)d_in[4];
    const float* ew  = (const float*)d_in[5];
    float* out = (float*)d_out;

    k_ged<<<1, 512, 0, stream>>>(Ag1, Ag2, l1, l2, nw, ew, out);
}

// Round 6
// 12.661 us; speedup vs baseline: 3.4734x; 1.2026x over previous
//
#include <hip/hip_runtime.h>
#include <hip/hip_bf16.h>

// Problem constants (from reference)
#define NL 10            // node label alphabet
#define NE 4             // edge label alphabet
#define N1 79
#define PAD 10           // pad pseudo-label index
#define NLP 11           // NL + pad
#define NODE_INS_DEL 0.03f
#define SINK_ITERS 10

// ---------------------------------------------------------------------------
// Label-space GED. S[i][j] = exp(-0.5*nodeC[lab1[i]][lab2[j]]) has only 11
// distinct row/col types (10 labels + pad). So:
//  * Sinkhorn collapses to 11-dim recurrences weighted by label counts
//  * v[i][j] = V[L1p[i]][L2p[j]],  V[P][S] = rho[P]*E_ext[P][S]*gam[S]
//  * Q_full  = sum_{a,b} T[a][b] * <M1[a], V*M2[b]*V^T>  where
//      M1[a][P][R] = #{(i,j): A1p[i,j]=a, L1p[j]=P, L1p[i]=R}   (note j->P!)
//      M2[b][S][T] = #{(k,l): A2p[k,l]=b, L2p[k]=S, L2p[l]=T}
//  * Diag = sum V[P][S]^2 * (N1d[.][P] T N2d[.][S]),  N*d = diagonal hists
//  * cv   = sum cnt1e[P]*cnt2e[S]*Cc[P][S]*V[P][S]
//  ged = cv + 0.5*(Q_full - Diag)
// One block, 512 threads: wave 0 does Sinkhorn while waves 1-7 histogram.
// Histogram loads are int4-vectorized; privatization copy = t&7 so copies
// vary across lanes (8x fewer same-address atomic serializations).
// ---------------------------------------------------------------------------
__global__ __launch_bounds__(512) void k_ged(
    const int* __restrict__ Ag1, const int* __restrict__ Ag2,
    const int* __restrict__ l1, const int* __restrict__ l2,
    const float* __restrict__ nw, const float* __restrict__ ew,
    float* __restrict__ dout)
{
    __shared__ float E_ext[121];        // exp(-0.5*cost) in label space (symmetric)
    __shared__ float Cc[121];           // node-cost in label space (with pad borders)
    __shared__ float T5[25];            // edge-pair cost table
    __shared__ float Vm[121];           // V = diag(rho) E_ext diag(gam)
    __shared__ int   lab1[N1], lab2[N1];
    __shared__ int   cnt1[NLP], cnt2[NLP];
    __shared__ __align__(16) int h1[8][605], h2[8][605];   // privatized histograms
    __shared__ int   nd1[55], nd2[55];         // diagonal histograms [a][P]
    __shared__ float M1f[605], M2f[605];
    __shared__ float N1f[55], N2f[55];
    __shared__ float rho[NLP], gam[NLP];
    __shared__ float Ub[605], Yb[605];
    __shared__ float redL[8];

    const int t = threadIdx.x;

    // ---------------- A0: zero (int4), load labels, build tables ----------
    {
        int4* hz1 = (int4*)&h1[0][0];   // 8*605 = 4840 ints = 1210 int4
        int4* hz2 = (int4*)&h2[0][0];
        const int4 z4 = make_int4(0, 0, 0, 0);
        for (int i = t; i < 1210; i += 512) { hz1[i] = z4; hz2[i] = z4; }
    }
    if (t < 55)  nd1[t] = 0;
    if (t >= 55 && t < 110) nd2[t - 55] = 0;
    if (t >= 158 && t < 168) cnt1[t - 158] = 0;
    if (t >= 168 && t < 178) cnt2[t - 168] = 0;
    if (t == 178) cnt1[PAD] = 1;
    if (t == 179) cnt2[PAD] = 1;
    if (t < N1)               lab1[t] = l1[t];
    if (t >= 79 && t < 158)   lab2[t - 79] = l2[t - 79];
    if (t >= 192 && t < 313) {          // E_ext + Cc (label space, incl pad)
        int q = t - 192, P = q / 11, S = q - P * 11;
        float cost;
        if (P < NL && S < NL) {
            if (P == S) cost = 0.f;
            else {
                int x = min(P, S), y = max(P, S);
                int pidx = x * (NL - 1) - x * (x - 1) / 2 + (y - x - 1);
                cost = fmaxf(nw[pidx], 0.f);
            }
        } else if (P == PAD && S == PAD) cost = 0.f;
        else cost = NODE_INS_DEL;
        Cc[q] = cost;
        E_ext[q] = __expf(-0.5f * cost);
    }
    if (t >= 320 && t < 345) {          // edge table 5x5
        int q = t - 320, a = q / 5, b = q - a * 5;
        float val;
        if (a == 0 && b == 0)       val = 0.f;
        else if (a == 0 || b == 0)  val = fmaxf(ew[NE * (NE - 1) / 2], 0.f);
        else if (a == b)            val = 0.f;
        else {
            int x = min(a, b) - 1, y = max(a, b) - 1;
            int p = x * (NE - 1) - x * (x - 1) / 2 + (y - x - 1);
            val = fmaxf(ew[p], 0.f);
        }
        T5[q] = val;
    }
    __syncthreads();

    // ---------------- A1: label counts ----------------
    if (t < N1)               atomicAdd(&cnt1[lab1[t]], 1);
    if (t >= 79 && t < 158)   atomicAdd(&cnt2[lab2[t - 79]], 1);
    __syncthreads();

    // ---------------- A2: Sinkhorn (wave 0) || histograms (waves 1-7) ----
    if (t < 64) {
        // Label-space Sinkhorn: lane = X*4+q; group of 4 lanes computes the
        // 11-term dot for label X (3 terms per lane), xor-reduced in-group.
        const int X = t >> 2, q = t & 3;
        const bool valid = (X < NLP);
        float ec2[3], ec1[3];
        #pragma unroll
        for (int k = 0; k < 3; ++k) {
            int M = 3 * q + k;
            if (valid && M < NLP) {
                float e = E_ext[X * 11 + M];
                ec2[k] = e * (float)cnt2[M];
                ec1[k] = e * (float)cnt1[M];
            } else { ec2[k] = 0.f; ec1[k] = 0.f; }
        }
        const int s0 = 4 * (3 * q + 0);
        const int s1 = 4 * (3 * q + 1);
        const int s2 = (3 * q + 2 < NLP) ? 4 * (3 * q + 2) : 0;  // clamp: weight is 0
        float gX = 1.0f, rX = 1.0f;
        for (int it = 0; it < SINK_ITERS; ++it) {
            float g0 = __shfl(gX, s0, 64);
            float g1 = __shfl(gX, s1, 64);
            float g2 = __shfl(gX, s2, 64);
            float y = ec2[0] * g0 + ec2[1] * g1 + ec2[2] * g2;
            y += __shfl_xor(y, 1, 64);
            y += __shfl_xor(y, 2, 64);
            rX = valid ? (1.0f / y) : 0.f;
            float r0 = __shfl(rX, s0, 64);
            float r1 = __shfl(rX, s1, 64);
            float r2 = __shfl(rX, s2, 64);
            float z = ec1[0] * r0 + ec1[1] * r1 + ec1[2] * r2;
            z += __shfl_xor(z, 1, 64);
            z += __shfl_xor(z, 2, 64);
            gX = valid ? (1.0f / z) : 0.f;
        }
        if (valid && q == 0) { rho[X] = rX; gam[X] = gX; }
    } else if (t < 288) {
        // graph-1 interior histogram: M1[a][lab1[j]][lab1[i]]
        int* hp = h1[t & 7];
        // pad borders (i=79 row / j=79 col of the padded 80x80):
        if (t >= 64 && t < 75)   atomicAdd(&h1[1][(t - 64) * 11 + 10], cnt1[t - 64]);
        if (t >= 80 && t < 90)   atomicAdd(&h1[1][110 + (t - 80)], cnt1[t - 80]);
        if (t >= 96 && t < 107)  atomicAdd(&h2[1][(t - 96) * 11 + 10], cnt2[t - 96]);
        if (t >= 112 && t < 122) atomicAdd(&h2[1][110 + (t - 112)], cnt2[t - 112]);
        // diagonal histograms (scattered loads; 2 wave-level issues total)
        if (t >= 64 && t < 64 + N1) {
            int j = t - 64;
            atomicAdd(&nd1[Ag1[j * 80] * 11 + lab1[j]], 1);   // A1[j][j]
        }
        if (t >= 144 && t < 144 + N1) {
            int k = t - 144;
            atomicAdd(&nd2[Ag2[k * 80] * 11 + lab2[k]], 1);
        }
        if (t == 224) nd1[10] = 1;   // pad diag: a=0, P=PAD
        if (t == 225) nd2[10] = 1;
        // interior stream, int4-vectorized (1560 full groups of 4)
        const int q = t - 64;
        #pragma unroll
        for (int itr = 0; itr < 7; ++itr) {
            int m = q + itr * 224;
            if (m < 1560) {
                int4 av = ((const int4*)Ag1)[m];
                int n0 = 4 * m;
                { int n = n0 + 0, i = n / 79, jj = n - i * 79;
                  atomicAdd(&hp[av.x * 121 + lab1[jj] * 11 + lab1[i]], 1); }
                { int n = n0 + 1, i = n / 79, jj = n - i * 79;
                  atomicAdd(&hp[av.y * 121 + lab1[jj] * 11 + lab1[i]], 1); }
                { int n = n0 + 2, i = n / 79, jj = n - i * 79;
                  atomicAdd(&hp[av.z * 121 + lab1[jj] * 11 + lab1[i]], 1); }
                { int n = n0 + 3, i = n / 79, jj = n - i * 79;
                  atomicAdd(&hp[av.w * 121 + lab1[jj] * 11 + lab1[i]], 1); }
            }
        }
        if (t == 64) {   // tail element n=6240 -> i=j=78
            int a = Ag1[6240];
            atomicAdd(&hp[a * 121 + lab1[78] * 11 + lab1[78]], 1);
        }
    } else {
        // graph-2 interior histogram: M2[b][lab2[k]][lab2[l]]
        int* hp = h2[t & 7];
        const int q = t - 288;
        #pragma unroll
        for (int itr = 0; itr < 7; ++itr) {
            int m = q + itr * 224;
            if (m < 1560) {
                int4 av = ((const int4*)Ag2)[m];
                int n0 = 4 * m;
                { int n = n0 + 0, k = n / 79, ll = n - k * 79;
                  atomicAdd(&hp[av.x * 121 + lab2[k] * 11 + lab2[ll]], 1); }
                { int n = n0 + 1, k = n / 79, ll = n - k * 79;
                  atomicAdd(&hp[av.y * 121 + lab2[k] * 11 + lab2[ll]], 1); }
                { int n = n0 + 2, k = n / 79, ll = n - k * 79;
                  atomicAdd(&hp[av.z * 121 + lab2[k] * 11 + lab2[ll]], 1); }
                { int n = n0 + 3, k = n / 79, ll = n - k * 79;
                  atomicAdd(&hp[av.w * 121 + lab2[k] * 11 + lab2[ll]], 1); }
            }
        }
        if (t == 288) {  // tail element n=6240 -> k=l=78
            int b = Ag2[6240];
            atomicAdd(&hp[b * 121 + lab2[78] * 11 + lab2[78]], 1);
        }
    }
    __syncthreads();

    // ---------------- B: reduce histogram copies; build V ----------------
    for (int i = t; i < 605; i += 512) {
        int s1v = 0, s2v = 0;
        #pragma unroll
        for (int w = 0; w < 8; ++w) { s1v += h1[w][i]; s2v += h2[w][i]; }
        M1f[i] = (float)s1v;
        M2f[i] = (float)s2v;
    }
    if (t < 55) { N1f[t] = (float)nd1[t]; N2f[t] = (float)nd2[t]; }
    if (t >= 64 && t < 185) {
        int q = t - 64;
        Vm[q] = rho[q / 11] * E_ext[q] * gam[q % 11];
    }
    __syncthreads();

    // ---------------- C: Ub[b][S][R] = sum_T M2[b][S][T] * V[R][T] -------
    for (int idx = t; idx < 605; idx += 512) {
        int b = idx / 121, r = idx - b * 121;
        int S = r / 11, R = r - S * 11;
        const float* m2 = &M2f[b * 121 + S * 11];
        const float* vr = &Vm[R * 11];
        float s = 0.f;
        #pragma unroll
        for (int T = 0; T < 11; ++T) s = fmaf(m2[T], vr[T], s);
        Ub[idx] = s;
    }
    __syncthreads();

    // ---------------- D: Yb[b][P][R] = sum_S V[P][S] * Ub[b][S][R] -------
    for (int idx = t; idx < 605; idx += 512) {
        int b = idx / 121, r = idx - b * 121;
        int P = r / 11, R = r - P * 11;
        float s = 0.f;
        #pragma unroll
        for (int S = 0; S < 11; ++S) s = fmaf(Vm[P * 11 + S], Ub[b * 121 + S * 11 + R], s);
        Yb[idx] = s;
    }
    __syncthreads();

    // ---------------- E: final contraction + reduce ----------------------
    float part = 0.f;
    if (t < 121) {
        int P = t / 11, R = t - P * 11;
        float qf = 0.f;
        #pragma unroll
        for (int a = 0; a < 5; ++a) {
            float sa = 0.f;
            #pragma unroll
            for (int b = 0; b < 5; ++b) sa = fmaf(T5[a * 5 + b], Yb[b * 121 + t], sa);
            qf = fmaf(M1f[a * 121 + t], sa, qf);
        }
        float sd = 0.f;
        #pragma unroll
        for (int a = 0; a < 5; ++a) {
            float sb = 0.f;
            #pragma unroll
            for (int b = 0; b < 5; ++b) sb = fmaf(T5[a * 5 + b], N2f[b * 11 + R], sb);
            sd = fmaf(N1f[a * 11 + P], sb, sd);
        }
        float vv = Vm[t];
        float dpart = vv * vv * sd;
        float cvp = (float)cnt1[P] * (float)cnt2[R] * Cc[t] * vv;
        part = cvp + 0.5f * (qf - dpart);
    }
    #pragma unroll
    for (int off = 1; off < 64; off <<= 1) part += __shfl_xor(part, off, 64);
    if ((t & 63) == 0) redL[t >> 6] = part;
    __syncthreads();
    if (t == 0) {
        float s = 0.f;
        #pragma unroll
        for (int w = 0; w < 8; ++w) s += redL[w];
        dout[0] = s;
    }
}

extern "C" void kernel_launch(void* const* d_in, const int* in_sizes, int n_in,
                              void* d_out, int out_size, void* d_ws, size_t ws_size,
                              hipStream_t stream) {
    const int*   Ag1 = (const int*)d_in[0];
    const int*   Ag2 = (const int*)d_in[1];
    const int*   l1  = (const int*)d_in[2];
    const int*   l2  = (const int*)d_in[3];
    const float* nw  = (const float*)d_in[4];
    const float* ew  = (const float*)d_in[5];
    float* out = (float*)d_out;

    k_ged<<<1, 512, 0, stream>>>(Ag1, Ag2, l1, l2, nw, ew, out);
}